// Round 7
// baseline (385.479 us; speedup 1.0000x reference)
//
#include <hip/hip_runtime.h>

#define NN 8192
#define INF_ 512
#define OUTF 256
#define LOG2E 1.4426950408889634f

typedef __attribute__((ext_vector_type(8))) short short8;
typedef __attribute__((ext_vector_type(4))) short short4v;
typedef __attribute__((ext_vector_type(4))) float f4;
typedef __attribute__((ext_vector_type(4))) int i4;

__device__ __forceinline__ unsigned short f2bf(float f) {
  union { float f; unsigned u; } v; v.f = f;
  unsigned r = v.u + 0x7fffu + ((v.u >> 16) & 1u);
  return (unsigned short)(r >> 16);
}
__device__ __forceinline__ float bf2f(unsigned short h) {
  union { unsigned u; float f; } v; v.u = ((unsigned)h) << 16;
  return v.f;
}

// ---------------- K0: W (512x256 f32) -> W^T hi/lo bf16 (256x512) ----------------
__global__ void k_wsplit(const float* __restrict__ W, unsigned short* __restrict__ Whi,
                         unsigned short* __restrict__ Wlo) {
  int idx = blockIdx.x * 256 + threadIdx.x;   // 131072
  int k = idx >> 8, c = idx & 255;
  float w = W[idx];
  unsigned short hi = f2bf(w);
  unsigned short lo = f2bf(w - bf2f(hi));
  Whi[c * INF_ + k] = hi;
  Wlo[c * INF_ + k] = lo;
}

// ---------------- K1: h = x@W (split-3 bf16 MFMA) -> hTl (j-tile-major), s1, s2 ----------------
// 512 blocks x 1 wave; block b: rows [b*16,+16), ALL 256 cols. a pre-scaled by LOG2E.
// hTl layout: [jt = j/32][col][j%32] bf16 -> k_attn B-frag loads are contiguous 1KB.
__global__ void __launch_bounds__(64) k_h(
    const float* __restrict__ x, const float* __restrict__ a,
    const unsigned short* __restrict__ Whi, const unsigned short* __restrict__ Wlo,
    unsigned short* __restrict__ hTl, float* __restrict__ s1, float* __restrict__ s2) {
  const int rowbase = blockIdx.x * 16;
  const int jt = blockIdx.x >> 1;        // 32-row j-tile index
  const int jhalf = blockIdx.x & 1;      // which 16-row half of the tile
  const int l = threadIdx.x;
  const int r15 = l & 15, kg = l >> 4;

  f4 acc[16];
#pragma unroll
  for (int i = 0; i < 16; ++i) acc[i] = (f4){0.f, 0.f, 0.f, 0.f};

  for (int kk = 0; kk < INF_; kk += 32) {
    const float* xp = x + (rowbase + r15) * INF_ + kk + kg * 8;
    f4 xa = *(const f4*)xp;
    f4 xb = *(const f4*)(xp + 4);
    short8 ahi, alo;
#pragma unroll
    for (int e = 0; e < 8; ++e) {
      float f = (e < 4) ? xa[e] : xb[e - 4];
      unsigned short h = f2bf(f);
      ahi[e] = (short)h;
      alo[e] = (short)f2bf(f - bf2f(h));
    }
#pragma unroll
    for (int cg = 0; cg < 16; ++cg) {
      int col = cg * 16 + r15;
      const short8 bhi = *(const short8*)(Whi + col * INF_ + kk + kg * 8);
      const short8 blo = *(const short8*)(Wlo + col * INF_ + kk + kg * 8);
      acc[cg] = __builtin_amdgcn_mfma_f32_16x16x32_bf16(ahi, bhi, acc[cg], 0, 0, 0);
      acc[cg] = __builtin_amdgcn_mfma_f32_16x16x32_bf16(ahi, blo, acc[cg], 0, 0, 0);
      acc[cg] = __builtin_amdgcn_mfma_f32_16x16x32_bf16(alo, bhi, acc[cg], 0, 0, 0);
    }
  }
  float sp1[4] = {0, 0, 0, 0}, sp2[4] = {0, 0, 0, 0};
#pragma unroll
  for (int cg = 0; cg < 16; ++cg) {
    int col = cg * 16 + r15;
    float a1v = a[col] * LOG2E, a2v = a[OUTF + col] * LOG2E;
    short4v hv;
#pragma unroll
    for (int r = 0; r < 4; ++r) {
      float v = acc[cg][r];
      hv[r] = (short)f2bf(v);
      sp1[r] += v * a1v;
      sp2[r] += v * a2v;
    }
    // hTl[jt][col][jhalf*16 + kg*4 + r]
    *(short4v*)(hTl + (size_t)jt * 8192 + col * 32 + jhalf * 16 + kg * 4) = hv;
  }
#pragma unroll
  for (int r = 0; r < 4; ++r) {
#pragma unroll
    for (int m = 1; m < 16; m <<= 1) {
      sp1[r] += __shfl_xor(sp1[r], m, 16);
      sp2[r] += __shfl_xor(sp2[r], m, 16);
    }
    if (r15 == 0) {
      s1[rowbase + kg * 4 + r] = sp1[r];
      s2[rowbase + kg * 4 + r] = sp2[r];
    }
  }
}

// ---------------- K2: fused attention, producer/consumer, all-contiguous HBM ----------------
// 512 blocks x 5 waves (320 thr). Block: 64 rows x 2048-j chunk (chunk=b&3, XCD-aligned).
// Wave 4 = producer: per 64-j strip, 16 global_load_lds of 1KB (4 rows x 256B contiguous,
//   source XOR-pre-swizzled / dest linear); its vmcnt queue is PURE glls, so the
//   __syncthreads drain IS the completion wait. Double-buffered 2x16KB.
// Waves 0-3 = consumers (2 row-halves x 2 col-halves): adj ints from swizzled LDS
//   (2-way banks, free), w=bf16(exp2(lr(s1'+s2'))) in-register, B-frags = contiguous
//   1KB L2 reads from hTl, 16 MFMA per 32-j sub-phase. One barrier per strip.
__global__ void __launch_bounds__(320) k_attn(
    const int* __restrict__ adj, const float* __restrict__ s1G,
    const float* __restrict__ s2G, const unsigned short* __restrict__ hTl,
    float* __restrict__ CP, float* __restrict__ lGp) {
  __shared__ int buf[2][4096];   // [2][64 rows][16 granules x 4 ints], granule-swizzled
  const int b = blockIdx.x;
  const int chunk = b & 3;
  const int rowbase = (b >> 2) * 64;
  const int jchunk = chunk * 2048;
  const int tid = threadIdx.x;
  const int wv = tid >> 6;
  const int l = tid & 63;

  if (wv == 4) {
    // ---------------- producer ----------------
    const int rloc = l >> 4;   // row-within-4
    const int gd = l & 15;     // dest granule
#define STAGE(bsel, p)                                                          \
    {                                                                           \
      _Pragma("unroll")                                                         \
      for (int i = 0; i < 16; ++i) {                                            \
        const int row = 4 * i + rloc;                                           \
        const char* src = (const char*)adj +                                    \
            (size_t)(rowbase + row) * 32768 + (size_t)(jchunk) * 4 +            \
            (size_t)(p) * 256 + ((gd ^ (row & 7)) << 4);                        \
        __builtin_amdgcn_global_load_lds(                                       \
            (const __attribute__((address_space(1))) unsigned int*)src,         \
            (__attribute__((address_space(3))) unsigned int*)                   \
                ((char*)&buf[bsel][0] + row * 256 + gd * 16), 16, 0, 0);        \
      }                                                                         \
    }
    STAGE(0, 0)
    __syncthreads();           // implicit vmcnt(0): strip 0 landed
    for (int p = 0; p < 32; ++p) {
      if (p < 31) STAGE((p + 1) & 1, p + 1)
      __syncthreads();         // publishes strip p+1; consumers done with strip p
    }
  } else {
    // ---------------- consumer ----------------
    const int rh = wv >> 1, ch = wv & 1;
    const int r15 = l & 15, kg = l >> 4;
    const float s1a = s1G[rowbase + rh * 32 + r15];        // pre-scaled by LOG2E
    const float s1b = s1G[rowbase + rh * 32 + 16 + r15];
    f4 acc[2][8];
#pragma unroll
    for (int rg = 0; rg < 2; ++rg)
#pragma unroll
      for (int cg = 0; cg < 8; ++cg) acc[rg][cg] = (f4){0.f, 0.f, 0.f, 0.f};
    float lsA = 0.f, lsB = 0.f;

    __syncthreads();           // strip 0 ready
    for (int p = 0; p < 32; ++p) {
      const char* bufc = (const char*)&buf[p & 1][0];
#pragma unroll
      for (int jt = 0; jt < 2; ++jt) {
        const int jtg = chunk * 64 + p * 2 + jt;
        // B-frags: contiguous 1KB per instruction from L2-resident hTl
        short8 bfr[8];
#pragma unroll
        for (int cg = 0; cg < 8; ++cg)
          bfr[cg] = *(const short8*)(hTl + (size_t)jtg * 8192 +
                                     (ch * 128 + cg * 16 + r15) * 32 + kg * 8);
        // s2 slice (L2 broadcast)
        const float* s2p = s2G + jchunk + (p * 2 + jt) * 32 + kg * 8;
        const f4 s20 = *(const f4*)s2p;
        const f4 s21 = *(const f4*)(s2p + 4);
        // A-frags: adj ints from swizzled LDS, w computed in-register
        short8 af[2];
#pragma unroll
        for (int rg = 0; rg < 2; ++rg) {
          const int rloc = rh * 32 + rg * 16 + r15;
          const int gb = jt * 8 + kg * 2;
          const i4 a0 = *(const i4*)(bufc + rloc * 256 + (((gb) ^ (rloc & 7)) << 4));
          const i4 a1 = *(const i4*)(bufc + rloc * 256 + (((gb + 1) ^ (rloc & 7)) << 4));
          const float s1v = rg ? s1b : s1a;
          float ls = 0.f;
#pragma unroll
          for (int e = 0; e < 8; ++e) {
            const int m = (e < 4) ? a0[e] : a1[e - 4];
            const float sv = (e < 4) ? s20[e] : s21[e - 4];
            float xx = s1v + sv;
            float lr = fmaxf(xx, 0.2f * xx);
            float pp = __builtin_amdgcn_exp2f(lr);
            float w0 = (m > 0) ? pp : 0.0f;
            unsigned short hh = f2bf(w0);
            af[rg][e] = (short)hh;
            ls += bf2f(hh);    // sum ROUNDED weights -> exact convex combination
          }
          if (rg) lsB += ls; else lsA += ls;
        }
#pragma unroll
        for (int cg = 0; cg < 8; ++cg) {
          acc[0][cg] = __builtin_amdgcn_mfma_f32_16x16x32_bf16(af[0], bfr[cg], acc[0][cg], 0, 0, 0);
          acc[1][cg] = __builtin_amdgcn_mfma_f32_16x16x32_bf16(af[1], bfr[cg], acc[1][cg], 0, 0, 0);
        }
      }
      __syncthreads();
    }

    // epilogue: lsum reduce over kg lanes; ch==0 stores. Plain stores of partials.
    lsA += __shfl_xor(lsA, 16, 64); lsA += __shfl_xor(lsA, 32, 64);
    lsB += __shfl_xor(lsB, 16, 64); lsB += __shfl_xor(lsB, 32, 64);
    if (ch == 0 && kg == 0) {
      lGp[chunk * NN + rowbase + rh * 32 + r15] = lsA;
      lGp[chunk * NN + rowbase + rh * 32 + 16 + r15] = lsB;
    }
    float* cp = CP + (size_t)chunk * NN * OUTF;
#pragma unroll
    for (int rg = 0; rg < 2; ++rg)
#pragma unroll
      for (int cg = 0; cg < 8; ++cg)
#pragma unroll
        for (int r = 0; r < 4; ++r)
          cp[(size_t)(rowbase + rh * 32 + rg * 16 + kg * 4 + r) * OUTF +
             ch * 128 + cg * 16 + r15] = acc[rg][cg][r];
  }
}

// ---------------- K3: out = (sum of 4 chunk-partials) / l + bias ----------------
__global__ void k_final(const float* __restrict__ CP, const float* __restrict__ lGp,
                        const float* __restrict__ bias, float* __restrict__ out) {
  const int idx = blockIdx.x * 256 + threadIdx.x;  // f4 index, 524288 total
  const int row = idx >> 6;
  const int c4 = idx & 63;
  const int CS = NN * OUTF / 4;   // chunk stride in f4
  f4 v0 = ((const f4*)CP)[idx];
  f4 v1 = ((const f4*)CP)[idx + CS];
  f4 v2 = ((const f4*)CP)[idx + 2 * CS];
  f4 v3 = ((const f4*)CP)[idx + 3 * CS];
  float lv = lGp[row] + lGp[NN + row] + lGp[2 * NN + row] + lGp[3 * NN + row];
  float inv = 1.0f / lv;
  f4 bb = ((const f4*)bias)[c4];
  f4 o;
#pragma unroll
  for (int e = 0; e < 4; ++e)
    o[e] = (v0[e] + v1[e] + v2[e] + v3[e]) * inv + bb[e];
  ((f4*)out)[idx] = o;
}

extern "C" void kernel_launch(void* const* d_in, const int* in_sizes, int n_in,
                              void* d_out, int out_size, void* d_ws, size_t ws_size,
                              hipStream_t stream) {
  const float* x = (const float*)d_in[0];
  const int* adj = (const int*)d_in[1];
  const float* W = (const float*)d_in[2];
  const float* a = (const float*)d_in[3];
  const float* bias = (const float*)d_in[4];
  float* out = (float*)d_out;

  char* ws = (char*)d_ws;
  float* CP  = (float*)(ws);                                  // 32 MB: 4 chunk-partials
  float* lGp = (float*)(ws + 33554432);                       // 128 KB: 4 x 8192
  unsigned short* hTl = (unsigned short*)(ws + 33685504);     // 4 MB  [256 jt][256 col][32 j]
  unsigned short* Whi = (unsigned short*)(ws + 37879808);     // 256 KB [256][512]
  unsigned short* Wlo = (unsigned short*)(ws + 38141952);     // 256 KB
  float* s1 = (float*)(ws + 38404096);                        // 32 KB
  float* s2 = (float*)(ws + 38436864);                        // 32 KB

  k_wsplit<<<512, 256, 0, stream>>>(W, Whi, Wlo);
  k_h<<<512, 64, 0, stream>>>(x, a, Whi, Wlo, hTl, s1, s2);
  k_attn<<<512, 320, 0, stream>>>(adj, s1, s2, hTl, CP, lGp);
  k_final<<<2048, 256, 0, stream>>>(CP, lGp, bias, out);
}

// Round 8
// 241.567 us; speedup vs baseline: 1.5957x; 1.5957x over previous
//
#include <hip/hip_runtime.h>

#define NN 8192
#define INF_ 512
#define OUTF 256
#define LOG2E 1.4426950408889634f

typedef __attribute__((ext_vector_type(8))) short short8;
typedef __attribute__((ext_vector_type(4))) short short4v;
typedef __attribute__((ext_vector_type(4))) float f4;
typedef __attribute__((ext_vector_type(4))) int i4;

__device__ __forceinline__ unsigned short f2bf(float f) {
  union { float f; unsigned u; } v; v.f = f;
  unsigned r = v.u + 0x7fffu + ((v.u >> 16) & 1u);
  return (unsigned short)(r >> 16);
}
__device__ __forceinline__ float bf2f(unsigned short h) {
  union { unsigned u; float f; } v; v.u = ((unsigned)h) << 16;
  return v.f;
}

// ---------------- K0: W (512x256 f32) -> W^T hi/lo bf16 (256x512) ----------------
__global__ void k_wsplit(const float* __restrict__ W, unsigned short* __restrict__ Whi,
                         unsigned short* __restrict__ Wlo) {
  int idx = blockIdx.x * 256 + threadIdx.x;   // 131072
  int k = idx >> 8, c = idx & 255;
  float w = W[idx];
  unsigned short hi = f2bf(w);
  unsigned short lo = f2bf(w - bf2f(hi));
  Whi[c * INF_ + k] = hi;
  Wlo[c * INF_ + k] = lo;
}

// ---------------- K1: h = x@W (split-3 bf16 MFMA) -> hTl (j-tile-major), s1, s2 ----------------
// 512 blocks x 1 wave; block b: rows [b*16,+16), ALL 256 cols. a pre-scaled by LOG2E.
// hTl layout: [jt = j/32][col][j%32] bf16 -> k_attn B-frag loads are contiguous 1KB.
__global__ void __launch_bounds__(64) k_h(
    const float* __restrict__ x, const float* __restrict__ a,
    const unsigned short* __restrict__ Whi, const unsigned short* __restrict__ Wlo,
    unsigned short* __restrict__ hTl, float* __restrict__ s1, float* __restrict__ s2) {
  const int rowbase = blockIdx.x * 16;
  const int jt = blockIdx.x >> 1;        // 32-row j-tile index
  const int jhalf = blockIdx.x & 1;      // which 16-row half of the tile
  const int l = threadIdx.x;
  const int r15 = l & 15, kg = l >> 4;

  f4 acc[16];
#pragma unroll
  for (int i = 0; i < 16; ++i) acc[i] = (f4){0.f, 0.f, 0.f, 0.f};

  for (int kk = 0; kk < INF_; kk += 32) {
    const float* xp = x + (rowbase + r15) * INF_ + kk + kg * 8;
    f4 xa = *(const f4*)xp;
    f4 xb = *(const f4*)(xp + 4);
    short8 ahi, alo;
#pragma unroll
    for (int e = 0; e < 8; ++e) {
      float f = (e < 4) ? xa[e] : xb[e - 4];
      unsigned short h = f2bf(f);
      ahi[e] = (short)h;
      alo[e] = (short)f2bf(f - bf2f(h));
    }
#pragma unroll
    for (int cg = 0; cg < 16; ++cg) {
      int col = cg * 16 + r15;
      const short8 bhi = *(const short8*)(Whi + col * INF_ + kk + kg * 8);
      const short8 blo = *(const short8*)(Wlo + col * INF_ + kk + kg * 8);
      acc[cg] = __builtin_amdgcn_mfma_f32_16x16x32_bf16(ahi, bhi, acc[cg], 0, 0, 0);
      acc[cg] = __builtin_amdgcn_mfma_f32_16x16x32_bf16(ahi, blo, acc[cg], 0, 0, 0);
      acc[cg] = __builtin_amdgcn_mfma_f32_16x16x32_bf16(alo, bhi, acc[cg], 0, 0, 0);
    }
  }
  float sp1[4] = {0, 0, 0, 0}, sp2[4] = {0, 0, 0, 0};
#pragma unroll
  for (int cg = 0; cg < 16; ++cg) {
    int col = cg * 16 + r15;
    float a1v = a[col] * LOG2E, a2v = a[OUTF + col] * LOG2E;
    short4v hv;
#pragma unroll
    for (int r = 0; r < 4; ++r) {
      float v = acc[cg][r];
      hv[r] = (short)f2bf(v);
      sp1[r] += v * a1v;
      sp2[r] += v * a2v;
    }
    *(short4v*)(hTl + (size_t)jt * 8192 + col * 32 + jhalf * 16 + kg * 4) = hv;
  }
#pragma unroll
  for (int r = 0; r < 4; ++r) {
#pragma unroll
    for (int m = 1; m < 16; m <<= 1) {
      sp1[r] += __shfl_xor(sp1[r], m, 16);
      sp2[r] += __shfl_xor(sp2[r], m, 16);
    }
    if (r15 == 0) {
      s1[rowbase + kg * 4 + r] = sp1[r];
      s2[rowbase + kg * 4 + r] = sp2[r];
    }
  }
}

// ---------------- K2: fused attention, 1-wave blocks, gll-pipelined, barrier-free ----------------
// 2048 blocks x 64 thr: c = b&7 (1024-j chunk == XCD), rows (b>>3)*32..+32.
// 16 strips of 64 j: adj staged by 8 global_load_lds (4 rows x 256B contiguous per instr,
// XOR-pre-swizzled source + linear dest + XOR read), double-buffered 2x8KB. No dest
// registers for the HBM stream -> no pressure-induced waits; ONLY counted vmcnt(8).
// B-frags: contiguous 1KB reads from XCD-local L2 (hTl). No barriers, no atomics.
__global__ void __launch_bounds__(64, 2) k_attn(
    const int* __restrict__ adj, const float* __restrict__ s1G,
    const float* __restrict__ s2G, const unsigned short* __restrict__ hTl,
    float* __restrict__ CP, float* __restrict__ lGp) {
  __shared__ int buf[2][2048];   // 2 x 8KB: [32 rows][16 slots x 16B], slot = g ^ (row&7)
  const int b = blockIdx.x;
  const int c = b & 7;
  const int rowbase = (b >> 3) * 32;
  const int l = threadIdx.x;
  const int r15 = l & 15, kg = l >> 4;

  const float s1_0 = s1G[rowbase + r15];        // pre-scaled by LOG2E
  const float s1_1 = s1G[rowbase + 16 + r15];

  f4 acc0[16], acc1[16];
#pragma unroll
  for (int cg = 0; cg < 16; ++cg) {
    acc0[cg] = (f4){0.f, 0.f, 0.f, 0.f};
    acc1[cg] = (f4){0.f, 0.f, 0.f, 0.f};
  }
  float lsum0 = 0.f, lsum1 = 0.f;

  // stage strip t (64 j) into buf[bsel]; source pre-swizzled so read-XOR finds it
#define STAGE(bsel, t)                                                            \
  {                                                                               \
    _Pragma("unroll")                                                             \
    for (int i = 0; i < 8; ++i) {                                                 \
      const int rloc = 4 * i + (l >> 4);                                          \
      const int gsrc = (l & 15) ^ (rloc & 7);                                     \
      const char* src = (const char*)adj + (size_t)(rowbase + rloc) * 32768 +     \
                        (size_t)c * 4096 + (size_t)(t) * 256 + gsrc * 16;         \
      __builtin_amdgcn_global_load_lds(                                           \
          (const __attribute__((address_space(1))) unsigned int*)src,             \
          (__attribute__((address_space(3))) unsigned int*)                       \
              ((char*)&buf[bsel][0] + i * 1024 + l * 16), 16, 0, 0);              \
    }                                                                             \
  }

  STAGE(0, 0)
  STAGE(1, 1)
  asm volatile("s_waitcnt vmcnt(8)" ::: "memory");   // strip 0 landed, strip 1 in flight
  __builtin_amdgcn_sched_barrier(0);

  for (int t = 0; t < 16; ++t) {
    const char* bp = (const char*)&buf[t & 1][0];
#pragma unroll
    for (int s = 0; s < 2; ++s) {
      const int jt = c * 32 + t * 2 + s;
      // B-frags: 16 contiguous 1KB loads from XCD-local L2
      short8 bfr[16];
#pragma unroll
      for (int cg = 0; cg < 16; ++cg)
        bfr[cg] = *(const short8*)(hTl + (size_t)jt * 8192 + (cg * 16 + r15) * 32 + kg * 8);
      // s2 slice (broadcast, L2)
      const float* s2p = s2G + c * 1024 + (t * 2 + s) * 32 + kg * 8;
      const f4 s20 = *(const f4*)s2p;
      const f4 s21 = *(const f4*)(s2p + 4);
      // adj from LDS (XOR slots; 2-way banks)
      const int g0 = s * 8 + kg * 2;
      const int r1 = 16 + r15;
      const i4 a00 = *(const i4*)(bp + r15 * 256 + ((g0 ^ (r15 & 7)) << 4));
      const i4 a01 = *(const i4*)(bp + r15 * 256 + (((g0 + 1) ^ (r15 & 7)) << 4));
      const i4 a10 = *(const i4*)(bp + r1 * 256 + ((g0 ^ (r1 & 7)) << 4));
      const i4 a11 = *(const i4*)(bp + r1 * 256 + (((g0 + 1) ^ (r1 & 7)) << 4));
      // w = adj ? exp2(leakyrelu(s1'+s2')) : 0 ; sum ROUNDED weights
      short8 af0, af1;
#pragma unroll
      for (int e = 0; e < 8; ++e) {
        const float sv = (e < 4) ? s20[e] : s21[e - 4];
        const int m0 = (e < 4) ? a00[e] : a01[e - 4];
        const int m1 = (e < 4) ? a10[e] : a11[e - 4];
        const float x0 = s1_0 + sv, x1 = s1_1 + sv;
        const float lr0 = fmaxf(x0, 0.2f * x0);
        const float lr1 = fmaxf(x1, 0.2f * x1);
        const float p0 = __builtin_amdgcn_exp2f(lr0);
        const float p1 = __builtin_amdgcn_exp2f(lr1);
        const float w0 = (m0 > 0) ? p0 : 0.0f;
        const float w1 = (m1 > 0) ? p1 : 0.0f;
        const unsigned short h0 = f2bf(w0), h1 = f2bf(w1);
        af0[e] = (short)h0; af1[e] = (short)h1;
        lsum0 += bf2f(h0); lsum1 += bf2f(h1);
      }
#pragma unroll
      for (int cg = 0; cg < 16; ++cg) {
        acc0[cg] = __builtin_amdgcn_mfma_f32_16x16x32_bf16(af0, bfr[cg], acc0[cg], 0, 0, 0);
        acc1[cg] = __builtin_amdgcn_mfma_f32_16x16x32_bf16(af1, bfr[cg], acc1[cg], 0, 0, 0);
      }
    }
    // refill the just-consumed buffer with strip t+2; keep it youngest in the queue
    if (t + 2 < 16) STAGE(t & 1, t + 2)
    asm volatile("s_waitcnt vmcnt(8)" ::: "memory");  // strip t+1 complete; t+2 in flight
    __builtin_amdgcn_sched_barrier(0);
  }

  // ---- epilogue: reduce lsum over kg, plain stores of chunk partials ----
  lsum0 += __shfl_xor(lsum0, 16, 64);
  lsum0 += __shfl_xor(lsum0, 32, 64);
  lsum1 += __shfl_xor(lsum1, 16, 64);
  lsum1 += __shfl_xor(lsum1, 32, 64);
  if (kg == 0) {
    lGp[c * NN + rowbase + r15] = lsum0;
    lGp[c * NN + rowbase + 16 + r15] = lsum1;
  }
  float* cp = CP + (size_t)c * NN * OUTF;
#pragma unroll
  for (int cg = 0; cg < 16; ++cg)
#pragma unroll
    for (int r = 0; r < 4; ++r) {
      const int col = cg * 16 + r15;
      cp[(size_t)(rowbase + kg * 4 + r) * OUTF + col] = acc0[cg][r];
      cp[(size_t)(rowbase + 16 + kg * 4 + r) * OUTF + col] = acc1[cg][r];
    }
#undef STAGE
}

// ---------------- K3: out = (sum of 8 chunk-partials) / l + bias ----------------
__global__ void k_final(const float* __restrict__ CP, const float* __restrict__ lGp,
                        const float* __restrict__ bias, float* __restrict__ out) {
  const int idx = blockIdx.x * 256 + threadIdx.x;  // f4 index, 524288 total
  const int row = idx >> 6;
  const int c4 = idx & 63;
  const int CS = NN * OUTF / 4;   // chunk stride in f4
  f4 v = ((const f4*)CP)[idx];
  float lv = lGp[row];
#pragma unroll
  for (int c = 1; c < 8; ++c) {
    f4 vc = ((const f4*)CP)[idx + c * CS];
#pragma unroll
    for (int e = 0; e < 4; ++e) v[e] += vc[e];
    lv += lGp[c * NN + row];
  }
  const float inv = 1.0f / lv;
  const f4 bb = ((const f4*)bias)[c4];
  f4 o;
#pragma unroll
  for (int e = 0; e < 4; ++e) o[e] = v[e] * inv + bb[e];
  ((f4*)out)[idx] = o;
}

extern "C" void kernel_launch(void* const* d_in, const int* in_sizes, int n_in,
                              void* d_out, int out_size, void* d_ws, size_t ws_size,
                              hipStream_t stream) {
  const float* x = (const float*)d_in[0];
  const int* adj = (const int*)d_in[1];
  const float* W = (const float*)d_in[2];
  const float* a = (const float*)d_in[3];
  const float* bias = (const float*)d_in[4];
  float* out = (float*)d_out;

  char* ws = (char*)d_ws;
  float* CP  = (float*)(ws);                                  // 64 MB: 8 chunk-partials
  float* lGp = (float*)(ws + 67108864);                       // 256 KB: 8 x 8192
  unsigned short* hTl = (unsigned short*)(ws + 67371008);     // 4 MB  [256 jt][256 col][32 j]
  unsigned short* Whi = (unsigned short*)(ws + 71565312);     // 256 KB [256][512]
  unsigned short* Wlo = (unsigned short*)(ws + 71827456);     // 256 KB
  float* s1 = (float*)(ws + 72089600);                        // 32 KB
  float* s2 = (float*)(ws + 72122368);                        // 32 KB

  k_wsplit<<<512, 256, 0, stream>>>(W, Whi, Wlo);
  k_h<<<512, 64, 0, stream>>>(x, a, Whi, Wlo, hTl, s1, s2);
  k_attn<<<2048, 64, 0, stream>>>(adj, s1, s2, hTl, CP, lGp);
  k_final<<<2048, 256, 0, stream>>>(CP, lGp, bias, out);
}

// Round 9
// 209.866 us; speedup vs baseline: 1.8368x; 1.1511x over previous
//
#include <hip/hip_runtime.h>

#define NN 8192
#define INF_ 512
#define OUTF 256
#define LOG2E 1.4426950408889634f

typedef __attribute__((ext_vector_type(8))) short short8;
typedef __attribute__((ext_vector_type(4))) short short4v;
typedef __attribute__((ext_vector_type(4))) float f4;
typedef __attribute__((ext_vector_type(4))) int i4;

__device__ __forceinline__ unsigned short f2bf(float f) {
  union { float f; unsigned u; } v; v.f = f;
  unsigned r = v.u + 0x7fffu + ((v.u >> 16) & 1u);
  return (unsigned short)(r >> 16);
}
__device__ __forceinline__ float bf2f(unsigned short h) {
  union { unsigned u; float f; } v; v.u = ((unsigned)h) << 16;
  return v.f;
}

// ---------------- K0: W (512x256 f32) -> W^T hi/lo bf16 (256x512) ----------------
__global__ void k_wsplit(const float* __restrict__ W, unsigned short* __restrict__ Whi,
                         unsigned short* __restrict__ Wlo) {
  int idx = blockIdx.x * 256 + threadIdx.x;   // 131072
  int k = idx >> 8, c = idx & 255;
  float w = W[idx];
  unsigned short hi = f2bf(w);
  unsigned short lo = f2bf(w - bf2f(hi));
  Whi[c * INF_ + k] = hi;
  Wlo[c * INF_ + k] = lo;
}

// ---------------- K1: h = x@W (split-3 bf16 MFMA) -> hTl tile-major, s1/s2 partials ----------------
// 1024 blocks x 1 wave (4 waves/CU): block b = rows [(b>>1)*16,+16) x col-half (b&1)*128.
// s1/s2 stored as 2 col-half partials (deterministic; k_wgen sums them).
__global__ void __launch_bounds__(64) k_h(
    const float* __restrict__ x, const float* __restrict__ a,
    const unsigned short* __restrict__ Whi, const unsigned short* __restrict__ Wlo,
    unsigned short* __restrict__ hTl, float* __restrict__ s1p, float* __restrict__ s2p) {
  const int b = blockIdx.x;
  const int rowbase = (b >> 1) * 16;
  const int ch = b & 1;
  const int colbase = ch * 128;
  const int jt = b >> 2;                 // 32-row j-tile of hTl
  const int jhalf = (b >> 1) & 1;        // 16-row half within the tile
  const int l = threadIdx.x;
  const int r15 = l & 15, kg = l >> 4;

  f4 acc[8];
#pragma unroll
  for (int i = 0; i < 8; ++i) acc[i] = (f4){0.f, 0.f, 0.f, 0.f};

  for (int kk = 0; kk < INF_; kk += 32) {
    const float* xp = x + (rowbase + r15) * INF_ + kk + kg * 8;
    f4 xa = *(const f4*)xp;
    f4 xb = *(const f4*)(xp + 4);
    short8 ahi, alo;
#pragma unroll
    for (int e = 0; e < 8; ++e) {
      float f = (e < 4) ? xa[e] : xb[e - 4];
      unsigned short h = f2bf(f);
      ahi[e] = (short)h;
      alo[e] = (short)f2bf(f - bf2f(h));
    }
#pragma unroll
    for (int cg = 0; cg < 8; ++cg) {
      int col = colbase + cg * 16 + r15;
      const short8 bhi = *(const short8*)(Whi + col * INF_ + kk + kg * 8);
      const short8 blo = *(const short8*)(Wlo + col * INF_ + kk + kg * 8);
      acc[cg] = __builtin_amdgcn_mfma_f32_16x16x32_bf16(ahi, bhi, acc[cg], 0, 0, 0);
      acc[cg] = __builtin_amdgcn_mfma_f32_16x16x32_bf16(ahi, blo, acc[cg], 0, 0, 0);
      acc[cg] = __builtin_amdgcn_mfma_f32_16x16x32_bf16(alo, bhi, acc[cg], 0, 0, 0);
    }
  }
  float sp1[4] = {0, 0, 0, 0}, sp2[4] = {0, 0, 0, 0};
#pragma unroll
  for (int cg = 0; cg < 8; ++cg) {
    int col = colbase + cg * 16 + r15;
    float a1v = a[col] * LOG2E, a2v = a[OUTF + col] * LOG2E;
    short4v hv;
#pragma unroll
    for (int r = 0; r < 4; ++r) {
      float v = acc[cg][r];
      hv[r] = (short)f2bf(v);
      sp1[r] += v * a1v;
      sp2[r] += v * a2v;
    }
    *(short4v*)(hTl + (size_t)jt * 8192 + col * 32 + jhalf * 16 + kg * 4) = hv;
  }
#pragma unroll
  for (int r = 0; r < 4; ++r) {
#pragma unroll
    for (int m = 1; m < 16; m <<= 1) {
      sp1[r] += __shfl_xor(sp1[r], m, 16);
      sp2[r] += __shfl_xor(sp2[r], m, 16);
    }
    if (r15 == 0) {
      s1p[ch * NN + rowbase + kg * 4 + r] = sp1[r];
      s2p[ch * NN + rowbase + kg * 4 + r] = sp2[r];
    }
  }
}

// ---------------- K2a: w-matrix gen, fully-contiguous streaming ----------------
// 8192 blocks x 256 thr (32 waves/CU); block = one adj row. Loads: 16B/lane i4,
// 1KB contiguous per wave-instruction. w written bf16 TILE-MAJOR [k/128][row][128]
// so k_av's LDS staging is 16KB-contiguous. Row-sum lG fused (ROUNDED weights).
__global__ void __launch_bounds__(256) k_wgen(
    const int* __restrict__ adj, const float* __restrict__ s1p,
    const float* __restrict__ s2p, unsigned short* __restrict__ w_t,
    float* __restrict__ lG) {
  __shared__ float red[4];
  const int row = blockIdx.x;
  const int tid = threadIdx.x;
  const float s1v = s1p[row] + s1p[NN + row];   // pre-scaled by LOG2E
  const i4* ap = (const i4*)(adj + (size_t)row * NN);
  const f4* sp0 = (const f4*)s2p;
  const f4* sp1 = (const f4*)(s2p + NN);
  float lsum = 0.f;

#pragma unroll
  for (int u = 0; u < 8; ++u) {
    const int q = u * 256 + tid;              // i4/f4 index (j/4); contiguous per wave
    i4 m = ap[q];
    f4 sva = sp0[q];
    f4 svb = sp1[q];
    short4v wp;
#pragma unroll
    for (int e = 0; e < 4; ++e) {
      float xx = s1v + sva[e] + svb[e];
      float lr = fmaxf(xx, 0.2f * xx);
      float pp = __builtin_amdgcn_exp2f(lr);
      float w0 = (m[e] > 0) ? pp : 0.0f;
      unsigned short hh = f2bf(w0);
      wp[e] = (short)hh;
      lsum += bf2f(hh);                       // sum ROUNDED weights (exact convex comb.)
    }
    const int kt = q >> 5;                    // k-panel (j/128)
    const int kin = (q & 31) * 4;             // element within panel row
    *(short4v*)(w_t + ((size_t)kt * NN + row) * 128 + kin) = wp;
  }

#pragma unroll
  for (int m = 1; m < 64; m <<= 1) lsum += __shfl_xor(lsum, m, 64);
  if ((tid & 63) == 0) red[tid >> 6] = lsum;
  __syncthreads();
  if (tid == 0) lG[row] = red[0] + red[1] + red[2] + red[3];
}

// ---------------- K2b: GEMM  CP[qt] = w[rows, kq] @ h[kq, cols] ----------------
// 512 blocks x 4 waves: rt=b>>2 (64 rows), qt=b&3 (K-quarter 2048). A staged via
// global_load_lds from TILE-MAJOR w_t (16KB contiguous per tile), 3-slot LDS,
// XOR-swizzled reads. B = contiguous 1KB loads from L2-resident hTl, issued
// BEFORE gll(t+2): the MFMA's auto-wait (vmcnt(16)) then retires gll(t+1)+B(t)
// while gll(t+2) stays in flight. ONE barrier per phase; no explicit vmcnt in loop.
__global__ void __launch_bounds__(256) k_av(
    const unsigned short* __restrict__ w_t, const unsigned short* __restrict__ hTl,
    float* __restrict__ CP) {
  __shared__ unsigned short At[3][8192];     // 3 x 16KB: [64 rows][128 k], XOR-16 swz
  const int b = blockIdx.x;
  const int rt = b >> 2, qt = b & 3;
  const int rowbase = rt * 64;
  const int ktile0 = qt * 16;                // first 128-k panel of this quarter
  const int tid = threadIdx.x;
  const int wv = tid >> 6, l = tid & 63;
  const int r15 = l & 15, kg = l >> 4;
  const int colbase = wv * 64;
  const char* wb = (const char*)w_t;

#define STAGE_A(slot, t)                                                          \
  {                                                                               \
    _Pragma("unroll")                                                             \
    for (int q = 0; q < 4; ++q) {                                                 \
      const int d = q * 4096 + tid * 16;      /* linear dest byte */              \
      const int r = d >> 8;                   /* tile row */                      \
      const int cb = d & 255;                 /* byte-in-row */                   \
      const int sc = cb ^ ((r & 7) << 4);     /* inverse swizzle on SOURCE */     \
      const char* src = wb + ((size_t)(ktile0 + (t)) * NN + rowbase + r) * 256 + sc; \
      __builtin_amdgcn_global_load_lds(                                           \
          (const __attribute__((address_space(1))) unsigned int*)src,             \
          (__attribute__((address_space(3))) unsigned int*)                       \
              ((char*)&At[slot][0] + d), 16, 0, 0);                               \
    }                                                                             \
  }

  f4 acc[4][4];
#pragma unroll
  for (int rg = 0; rg < 4; ++rg)
#pragma unroll
    for (int cg = 0; cg < 4; ++cg) acc[rg][cg] = (f4){0.f, 0.f, 0.f, 0.f};

  // prologue: stage tiles 0,1; wait tile 0 (leave tile 1 in flight)
  STAGE_A(0, 0)
  STAGE_A(1, 1)
  asm volatile("s_waitcnt vmcnt(16)" ::: "memory");
  __builtin_amdgcn_s_barrier();

  for (int t = 0; t < 16; ++t) {
    // ---- B(t) FIRST: 16 contiguous-1KB L2 loads ----
    short8 Bf[4][4];
#pragma unroll
    for (int ks = 0; ks < 4; ++ks)
#pragma unroll
      for (int cg = 0; cg < 4; ++cg)
        Bf[ks][cg] = *(const short8*)(hTl + (size_t)(qt * 64 + t * 4 + ks) * 8192 +
                                      (colbase + cg * 16 + r15) * 32 + kg * 8);
    // ---- gll(t+2) AFTER B: youngest in queue, survives the MFMA auto-wait ----
    if (t + 2 < 16) STAGE_A((t + 2) % 3, t + 2)
    // ---- A from LDS (swizzled) + 64 MFMAs; compiler's B-wait = vmcnt(16) ----
#pragma unroll
    for (int ks = 0; ks < 4; ++ks)
#pragma unroll
      for (int rg = 0; rg < 4; ++rg) {
        const int r = rg * 16 + r15;
        const int byte = (r * 256 + ks * 64 + kg * 16) ^ ((r & 7) << 4);
        const short8 Af = *(const short8*)((const char*)&At[t % 3][0] + byte);
#pragma unroll
        for (int cg = 0; cg < 4; ++cg)
          acc[rg][cg] = __builtin_amdgcn_mfma_f32_16x16x32_bf16(Af, Bf[ks][cg], acc[rg][cg], 0, 0, 0);
      }
    // every wave passed its B(t)-wait => gll(t+1) retired in all waves; safe to
    // read At[(t+1)%3] next phase and overwrite At[(t+2)%3] (read at t-1).
    __builtin_amdgcn_s_barrier();
  }

  // epilogue: plain stores to quarter-partial
  float* cp = CP + (size_t)qt * NN * OUTF;
#pragma unroll
  for (int rg = 0; rg < 4; ++rg)
#pragma unroll
    for (int cg = 0; cg < 4; ++cg)
#pragma unroll
      for (int r = 0; r < 4; ++r)
        cp[(size_t)(rowbase + rg * 16 + kg * 4 + r) * OUTF + colbase + cg * 16 + r15] =
            acc[rg][cg][r];
#undef STAGE_A
}

// ---------------- K3: out = (sum of 4 K-quarter partials) / l + bias ----------------
__global__ void k_final(const float* __restrict__ CP, const float* __restrict__ lG,
                        const float* __restrict__ bias, float* __restrict__ out) {
  const int idx = blockIdx.x * 256 + threadIdx.x;  // f4 index, 524288 total
  const int row = idx >> 6;
  const int c4 = idx & 63;
  const int CS = NN * OUTF / 4;   // quarter stride in f4
  f4 v0 = ((const f4*)CP)[idx];
  f4 v1 = ((const f4*)CP)[idx + CS];
  f4 v2 = ((const f4*)CP)[idx + 2 * CS];
  f4 v3 = ((const f4*)CP)[idx + 3 * CS];
  float inv = 1.0f / lG[row];
  f4 bb = ((const f4*)bias)[c4];
  f4 o;
#pragma unroll
  for (int e = 0; e < 4; ++e)
    o[e] = (v0[e] + v1[e] + v2[e] + v3[e]) * inv + bb[e];
  ((f4*)out)[idx] = o;
}

extern "C" void kernel_launch(void* const* d_in, const int* in_sizes, int n_in,
                              void* d_out, int out_size, void* d_ws, size_t ws_size,
                              hipStream_t stream) {
  const float* x = (const float*)d_in[0];
  const int* adj = (const int*)d_in[1];
  const float* W = (const float*)d_in[2];
  const float* a = (const float*)d_in[3];
  const float* bias = (const float*)d_in[4];
  float* out = (float*)d_out;

  char* ws = (char*)d_ws;
  unsigned short* w_t = (unsigned short*)(ws);                // 128 MB [64 kt][8192 row][128 k]
  float* CP  = (float*)(ws + 134217728);                      // 32 MB  4 x [8192][256] f32
  float* lG  = (float*)(ws + 167772160);                      // 32 KB
  unsigned short* hTl = (unsigned short*)(ws + 167804928);    // 4 MB   [256 jt][256 col][32 j]
  unsigned short* Whi = (unsigned short*)(ws + 171999232);    // 256 KB [256][512]
  unsigned short* Wlo = (unsigned short*)(ws + 172261376);    // 256 KB
  float* s1p = (float*)(ws + 172523520);                      // 64 KB  2 x 8192
  float* s2p = (float*)(ws + 172589056);                      // 64 KB  2 x 8192

  k_wsplit<<<512, 256, 0, stream>>>(W, Whi, Wlo);
  k_h<<<1024, 64, 0, stream>>>(x, a, Whi, Wlo, hTl, s1p, s2p);
  k_wgen<<<8192, 256, 0, stream>>>(adj, s1p, s2p, w_t, lG);
  k_av<<<512, 256, 0, stream>>>(w_t, hTl, CP);
  k_final<<<2048, 256, 0, stream>>>(CP, lG, bias, out);
}